// Round 1
// baseline (180.994 us; speedup 1.0000x reference)
//
#include <hip/hip_runtime.h>

// TextureMartingaleModule: per-pixel 3x3 GLCM-style features on (8,16,256,256) f32,
// output (8,64,256,256) f32 with channel-major feature interleave (outc = c*4 + f).
// M = exp(theta*log(feat+EPS) - 0.5*theta^2), theta=1 -> (feat+EPS)*exp(-0.5).

#define GLCM_EPS 1e-6f
#define INV_SQRT_E 0.60653065971263342f  // exp(-0.5)

__global__ __launch_bounds__(256) void glcm_martingale_kernel(
    const float* __restrict__ x, float* __restrict__ out) {
  const int H = 256, W = 256, HW = H * W;

  int tid = blockIdx.x * 256 + threadIdx.x;   // one thread per (b,c,h,w)
  int bc  = tid >> 16;                        // b*C + c   (HW = 2^16)
  int rem = tid & (HW - 1);
  int h   = rem >> 8;
  int w   = rem & (W - 1);

  const float* __restrict__ plane = x + (size_t)bc * HW;

  // 3x3 window with zero padding, kept in registers.
  float p[9];
#pragma unroll
  for (int dy = -1; dy <= 1; ++dy) {
    int hh = h + dy;
    bool rv = ((unsigned)hh < (unsigned)H);
#pragma unroll
    for (int dx = -1; dx <= 1; ++dx) {
      int ww = w + dx;
      bool v = rv && ((unsigned)ww < (unsigned)W);
      p[(dy + 1) * 3 + (dx + 1)] = v ? plane[hh * W + ww] : 0.0f;
    }
  }

  float sum = 0.0f, sum2 = 0.0f, sumplog = 0.0f;
#pragma unroll
  for (int i = 0; i < 9; ++i) {
    float pi = p[i];
    sum += pi;
    sum2 += pi * pi;
    sumplog += pi * __logf(pi + GLCM_EPS);  // p=0 taps contribute exactly 0
  }
  const float inv9 = 1.0f / 9.0f;
  float mean = sum * inv9;

  // Second pass: exact deviations (avoids sum2 - sum^2/9 cancellation).
  float S = 0.0f, sabs = 0.0f;
#pragma unroll
  for (int i = 0; i < 9; ++i) {
    float d = p[i] - mean;
    S += d * d;
    sabs += fabsf(d);
  }

  float stdv = sqrtf(S * 0.125f) + GLCM_EPS;      // ddof=1: sqrt(S/8) + eps
  float contrast = (S * inv9) / (stdv * stdv);
  float energy = sum2 * inv9;
  float entropy = -sumplog * inv9;
  float homog = 1.0f / (1.0f + sabs * inv9);

  // Output: [B, C*4, H, W], channel-major feature order
  // {contrast, energy, entropy, homogeneity}.
  size_t obase = (size_t)bc * 4 * HW + rem;
  out[obase]           = (contrast + GLCM_EPS) * INV_SQRT_E;
  out[obase + HW]      = (energy   + GLCM_EPS) * INV_SQRT_E;
  out[obase + 2 * HW]  = (entropy  + GLCM_EPS) * INV_SQRT_E;
  out[obase + 3 * HW]  = (homog    + GLCM_EPS) * INV_SQRT_E;
}

extern "C" void kernel_launch(void* const* d_in, const int* in_sizes, int n_in,
                              void* d_out, int out_size, void* d_ws, size_t ws_size,
                              hipStream_t stream) {
  const float* x = (const float*)d_in[0];
  float* out = (float*)d_out;
  // B*C*H*W = 8*16*256*256 = 8,388,608 threads -> 32768 blocks of 256.
  const int total = 8 * 16 * 256 * 256;
  dim3 grid(total / 256), block(256);
  glcm_martingale_kernel<<<grid, block, 0, stream>>>(x, out);
}

// Round 2
// 160.676 us; speedup vs baseline: 1.1265x; 1.1265x over previous
//
#include <hip/hip_runtime.h>

// TextureMartingaleModule: 3x3 zero-padded GLCM features on (8,16,256,256) f32.
// Out (8,64,256,256) f32, outc = c*4 + {contrast, energy, entropy, homogeneity}.
// M = exp(log(f+EPS) - 0.5) = (f+EPS)*exp(-0.5)  (theta=1).
//
// Layout: one wave (64 lanes) = one image row (64 lanes x 4 px = 256 = W).
// Each lane float4-loads rows h-1,h,h+1 at its 4 columns; +-1 column halo via
// __shfl (no LDS). Column partials (sum, sum^2, p*log p) shared across the
// thread's 4 pixels -> 18 logs / 4 px instead of 36.

#define GLCM_EPS 1e-6f
#define INV_SQRT_E 0.60653065971263342f  // exp(-0.5)

__global__ __launch_bounds__(256) void glcm_martingale_kernel(
    const float* __restrict__ x, float* __restrict__ out) {
  const int W = 256, HW = 256 * 256;

  const int lane = threadIdx.x & 63;
  const int wave = threadIdx.x >> 6;
  const int row  = blockIdx.x * 4 + wave;  // global row over all 128 planes
  const int bc   = row >> 8;               // plane index (b*C + c)
  const int h    = row & 255;
  const int w0   = lane << 2;              // first of this thread's 4 columns

  const float* __restrict__ plane = x + (size_t)bc * HW;

  const float4 z4 = make_float4(0.f, 0.f, 0.f, 0.f);
  float4 v[3];
  v[0] = (h > 0)   ? *reinterpret_cast<const float4*>(plane + (h - 1) * W + w0) : z4;
  v[1] =             *reinterpret_cast<const float4*>(plane + h * W + w0);
  v[2] = (h < 255) ? *reinterpret_cast<const float4*>(plane + (h + 1) * W + w0) : z4;

  // 6-wide windows per row: [left, x, y, z, w, right]
  float win[3][6];
#pragma unroll
  for (int r = 0; r < 3; ++r) {
    float L = __shfl_up(v[r].w, 1);
    float R = __shfl_down(v[r].x, 1);
    if (lane == 0)  L = 0.f;   // zero pad at w = -1
    if (lane == 63) R = 0.f;   // zero pad at w = 256
    win[r][0] = L;      win[r][1] = v[r].x; win[r][2] = v[r].y;
    win[r][3] = v[r].z; win[r][4] = v[r].w; win[r][5] = R;
  }

  // Column partials shared by the 4 pixels.
  float cs[6], cs2[6], cpl[6];
#pragma unroll
  for (int c = 0; c < 6; ++c) {
    float a = win[0][c], b = win[1][c], d = win[2][c];
    cs[c]  = a + b + d;
    cs2[c] = a * a + b * b + d * d;
    // p=0 taps: 0*log(eps) == 0 exactly, matches zero padding contribution.
    cpl[c] = a * __logf(a + GLCM_EPS) + b * __logf(b + GLCM_EPS) +
             d * __logf(d + GLCM_EPS);
  }

  const float inv9 = 1.0f / 9.0f;
  float fo[4][4];  // [feature][pixel]
#pragma unroll
  for (int j = 0; j < 4; ++j) {
    float sum  = cs[j]  + cs[j + 1]  + cs[j + 2];
    float sum2 = cs2[j] + cs2[j + 1] + cs2[j + 2];
    float spl  = cpl[j] + cpl[j + 1] + cpl[j + 2];
    float mean = sum * inv9;

    float S = 0.f, sab = 0.f;
#pragma unroll
    for (int r = 0; r < 3; ++r) {
#pragma unroll
      for (int c = 0; c < 3; ++c) {
        float d = win[r][j + c] - mean;
        S += d * d;
        sab += fabsf(d);
      }
    }
    float stdv = sqrtf(S * 0.125f) + GLCM_EPS;  // ddof=1
    fo[0][j] = (S * inv9) / (stdv * stdv);      // contrast
    fo[1][j] = sum2 * inv9;                     // energy
    fo[2][j] = -spl * inv9;                     // entropy
    fo[3][j] = 1.0f / (1.0f + sab * inv9);      // homogeneity
  }

  const size_t obase = (size_t)bc * 4 * HW + h * W + w0;
#pragma unroll
  for (int f = 0; f < 4; ++f) {
    float4 o = make_float4((fo[f][0] + GLCM_EPS) * INV_SQRT_E,
                           (fo[f][1] + GLCM_EPS) * INV_SQRT_E,
                           (fo[f][2] + GLCM_EPS) * INV_SQRT_E,
                           (fo[f][3] + GLCM_EPS) * INV_SQRT_E);
    *reinterpret_cast<float4*>(out + obase + (size_t)f * HW) = o;
  }
}

extern "C" void kernel_launch(void* const* d_in, const int* in_sizes, int n_in,
                              void* d_out, int out_size, void* d_ws, size_t ws_size,
                              hipStream_t stream) {
  const float* x = (const float*)d_in[0];
  float* out = (float*)d_out;
  // 128 planes * 256 rows = 32768 rows; 4 rows (waves) per 256-thread block.
  dim3 grid(32768 / 4), block(256);
  glcm_martingale_kernel<<<grid, block, 0, stream>>>(x, out);
}

// Round 3
// 158.749 us; speedup vs baseline: 1.1401x; 1.0121x over previous
//
#include <hip/hip_runtime.h>

// TextureMartingaleModule: 3x3 zero-padded GLCM features on (8,16,256,256) f32.
// Out (8,64,256,256) f32, outc = c*4 + {contrast, energy, entropy, homogeneity}.
// M = exp(log(f+EPS) - 0.5) = (f+EPS)*exp(-0.5)  (theta=1).
//
// One wave = one 4-row x 256-col stripe of one plane. Lane handles 4 columns.
// Loads 6 input rows (float4/lane), interior rows reused across the 4 output
// rows: 1.5 row-loads per output row instead of 3, and p*log(p) computed once
// per element per wave (2.25 logs/px instead of 4.5). Column halo via __shfl.

#define GLCM_EPS 1e-6f
#define INV_SQRT_E 0.60653065971263342f  // exp(-0.5)

__global__ __launch_bounds__(256) void glcm_martingale_kernel(
    const float* __restrict__ x, float* __restrict__ out) {
  const int W = 256, HW = 256 * 256;

  const int lane   = threadIdx.x & 63;
  const int wv     = threadIdx.x >> 6;
  const int stripe = blockIdx.x * 4 + wv;   // 8192 stripes total
  const int bc     = stripe >> 6;           // plane (b*C + c); 64 stripes/plane
  const int h0     = (stripe & 63) << 2;    // first output row: 0..252
  const int w0     = lane << 2;             // first of this lane's 4 columns

  const float* __restrict__ plane = x + (size_t)bc * HW;
  const float4 z4 = make_float4(0.f, 0.f, 0.f, 0.f);

  // 6 input rows (h0-1 .. h0+4), 6-wide per lane: [left, x, y, z, w, right]
  float win[6][6];
  float pl[6][6];  // p * log(p + eps), computed once per element
#pragma unroll
  for (int r = 0; r < 6; ++r) {
    int hh = h0 + r - 1;
    float4 v = ((unsigned)hh < 256u)
                   ? *reinterpret_cast<const float4*>(plane + hh * W + w0)
                   : z4;
    float L = __shfl_up(v.w, 1);
    float R = __shfl_down(v.x, 1);
    if (lane == 0)  L = 0.f;   // zero pad at w = -1
    if (lane == 63) R = 0.f;   // zero pad at w = 256
    win[r][0] = L;   win[r][1] = v.x; win[r][2] = v.y;
    win[r][3] = v.z; win[r][4] = v.w; win[r][5] = R;
#pragma unroll
    for (int c = 0; c < 6; ++c) {
      float p = win[r][c];
      pl[r][c] = p * __logf(p + GLCM_EPS);  // p=0 taps contribute exactly 0
    }
  }

  const float inv9 = 1.0f / 9.0f;
  const size_t obase0 = (size_t)bc * 4 * HW + (size_t)h0 * W + w0;

#pragma unroll
  for (int j = 0; j < 4; ++j) {  // output row h0 + j, input rows j..j+2
    float cs[6], cs2[6], cpl[6];
#pragma unroll
    for (int c = 0; c < 6; ++c) {
      float a = win[j][c], b = win[j + 1][c], d = win[j + 2][c];
      cs[c]  = a + b + d;
      cs2[c] = a * a + b * b + d * d;
      cpl[c] = pl[j][c] + pl[j + 1][c] + pl[j + 2][c];
    }

    float fo[4][4];  // [feature][pixel]
#pragma unroll
    for (int jj = 0; jj < 4; ++jj) {
      float sum  = cs[jj]  + cs[jj + 1]  + cs[jj + 2];
      float sum2 = cs2[jj] + cs2[jj + 1] + cs2[jj + 2];
      float spl  = cpl[jj] + cpl[jj + 1] + cpl[jj + 2];
      float mean = sum * inv9;

      float S = 0.f, sab = 0.f;  // explicit deviations: no cancellation
#pragma unroll
      for (int r = 0; r < 3; ++r) {
#pragma unroll
        for (int c = 0; c < 3; ++c) {
          float d = win[j + r][jj + c] - mean;
          S += d * d;
          sab += fabsf(d);
        }
      }
      float stdv = sqrtf(S * 0.125f) + GLCM_EPS;  // ddof=1
      fo[0][jj] = (S * inv9) / (stdv * stdv);     // contrast
      fo[1][jj] = sum2 * inv9;                    // energy
      fo[2][jj] = -spl * inv9;                    // entropy
      fo[3][jj] = 1.0f / (1.0f + sab * inv9);     // homogeneity
    }

    const size_t ob = obase0 + (size_t)j * W;
#pragma unroll
    for (int f = 0; f < 4; ++f) {
      float4 o = make_float4((fo[f][0] + GLCM_EPS) * INV_SQRT_E,
                             (fo[f][1] + GLCM_EPS) * INV_SQRT_E,
                             (fo[f][2] + GLCM_EPS) * INV_SQRT_E,
                             (fo[f][3] + GLCM_EPS) * INV_SQRT_E);
      *reinterpret_cast<float4*>(out + ob + (size_t)f * HW) = o;
    }
  }
}

extern "C" void kernel_launch(void* const* d_in, const int* in_sizes, int n_in,
                              void* d_out, int out_size, void* d_ws, size_t ws_size,
                              hipStream_t stream) {
  const float* x = (const float*)d_in[0];
  float* out = (float*)d_out;
  // 128 planes * 64 stripes = 8192 waves; 4 waves per 256-thread block.
  dim3 grid(8192 / 4), block(256);
  glcm_martingale_kernel<<<grid, block, 0, stream>>>(x, out);
}